// Round 1
// baseline (1107.760 us; speedup 1.0000x reference)
//
#include <hip/hip_runtime.h>
#include <math.h>

#define Nn1024 1024
#define INF_ 1000000.0f
#define EPS_ 1e-5f

// ---------------- workspace layout (float offsets) ----------------
static const size_t O_U   = 0;                     // u[128][8]
static const size_t O_WBB = 1024;                  // wbb[64][8]
static const size_t O_SU  = 1536;                  // su[8]
static const size_t O_CB  = 1544;                  // cb[8]
static const size_t O_NN  = 2048;                  // node_n [1024][256]
static const size_t O_QR  = O_NN + 262144;         // q raw  [1024][384]
static const size_t O_KR  = O_QR + 393216;         // k raw
static const size_t O_V   = O_KR + 393216;         // v
static const size_t O_GR  = O_V  + 393216;         // gate raw (pre-bias/sigmoid)
static const size_t O_Q   = O_GR + 393216;         // q roped*scale
static const size_t O_K   = O_Q  + 393216;         // k roped
static const size_t O_M   = O_K  + 393216;         // row max [8][1024]
static const size_t O_L   = O_M  + 8192;           // row sum [8][1024]
static const size_t O_OT  = O_L  + 8192;           // O^T [8][48][1024] (gated)
static const size_t O_G   = O_OT + 393216;         // post-Wo [1024][256]
static const size_t O_GN  = O_G  + 262144;         // LN(post-Wo)
static const size_t O_H1  = O_GN + 262144;         // relu(h@W1+b1) [1024][512]
static const size_t O_BT  = O_H1 + 524288;         // S/b_term [8][1024][1024]

// ---------------- K0: tiny precompute tables ----------------
__global__ void prep_kernel(const float* __restrict__ g_edge, const float* __restrict__ b_edge,
                            const float* __restrict__ W_bias, const float* __restrict__ Wb,
                            float* __restrict__ ws) {
    int t = threadIdx.x; // 512 threads
    for (int i = t; i < 1024; i += 512) {
        int c = i >> 3;
        ws[O_U + i] = g_edge[c] * Wb[i];
    }
    {   // wbb = W_bias @ Wb  (64x8)
        int d = t >> 3, h = t & 7;
        float s = 0.f;
        for (int c = 0; c < 128; c++) s += W_bias[d * 128 + c] * Wb[c * 8 + h];
        ws[O_WBB + t] = s;
    }
    if (t < 8) {
        float s = 0.f, cbv = 0.f;
        for (int c = 0; c < 128; c++) {
            s   += g_edge[c] * Wb[c * 8 + t];
            cbv += b_edge[c] * Wb[c * 8 + t];
        }
        ws[O_SU + t] = s;
        ws[O_CB + t] = cbv;
    }
}

// ---------------- K1: fused edge-LN + bias@W_bias + @Wb -> b_term[h][i][j] ----------------
// 256 pairs per block, thread-per-pair. Edge staged in two 64-col chunks + bias chunk
// through a single 64KB LDS buffer, XOR-swizzled so per-thread row reads are conflict-free.
__device__ __forceinline__ int swz(int p, int c) { return (p << 6) | (c ^ (p & 31)); }

__global__ __launch_bounds__(256, 2) void bterm_kernel(
    const float* __restrict__ edge, const float* __restrict__ bias,
    const float* __restrict__ u, const float* __restrict__ wbb,
    const float* __restrict__ su, const float* __restrict__ cb,
    float* __restrict__ bt)
{
    __shared__ float lds[256 * 64]; // 64 KB
    const int t = threadIdx.x;
    const size_t p0 = (size_t)blockIdx.x * 256;

    float s1 = 0.f, s2 = 0.f;
    float d[8] = {0.f,0.f,0.f,0.f,0.f,0.f,0.f,0.f};
    float bb[8] = {0.f,0.f,0.f,0.f,0.f,0.f,0.f,0.f};

    for (int ch = 0; ch < 2; ch++) {
        __syncthreads();
        float4 tmp[16];
        #pragma unroll
        for (int it = 0; it < 16; it++) {
            int idx = (it << 8) + t;
            int p = idx >> 4, c4 = (idx & 15) << 2;
            tmp[it] = *(const float4*)(edge + (p0 + p) * 128 + ch * 64 + c4);
        }
        #pragma unroll
        for (int it = 0; it < 16; it++) {
            int idx = (it << 8) + t;
            int p = idx >> 4, c4 = (idx & 15) << 2;
            lds[swz(p, c4 + 0)] = tmp[it].x;
            lds[swz(p, c4 + 1)] = tmp[it].y;
            lds[swz(p, c4 + 2)] = tmp[it].z;
            lds[swz(p, c4 + 3)] = tmp[it].w;
        }
        __syncthreads();
        const float* urow = u + ch * 512;
        for (int c = 0; c < 64; c++) {
            float e = lds[swz(t, c)];
            s1 += e;
            s2 = fmaf(e, e, s2);
            #pragma unroll
            for (int h = 0; h < 8; h++) d[h] = fmaf(e, urow[c * 8 + h], d[h]);
        }
    }
    // bias phase
    __syncthreads();
    {
        float4 tmp[16];
        #pragma unroll
        for (int it = 0; it < 16; it++) {
            int idx = (it << 8) + t;
            int p = idx >> 4, c4 = (idx & 15) << 2;
            tmp[it] = *(const float4*)(bias + (p0 + p) * 64 + c4);
        }
        #pragma unroll
        for (int it = 0; it < 16; it++) {
            int idx = (it << 8) + t;
            int p = idx >> 4, c4 = (idx & 15) << 2;
            lds[swz(p, c4 + 0)] = tmp[it].x;
            lds[swz(p, c4 + 1)] = tmp[it].y;
            lds[swz(p, c4 + 2)] = tmp[it].z;
            lds[swz(p, c4 + 3)] = tmp[it].w;
        }
        __syncthreads();
        for (int c = 0; c < 64; c++) {
            float bv = lds[swz(t, c)];
            #pragma unroll
            for (int h = 0; h < 8; h++) bb[h] = fmaf(bv, wbb[c * 8 + h], bb[h]);
        }
    }
    const float m  = s1 * 0.0078125f;
    const float var = s2 * 0.0078125f - m * m;
    const float rs = rsqrtf(var + EPS_);
    const size_t p = p0 + t;
    #pragma unroll
    for (int h = 0; h < 8; h++)
        bt[(size_t)h * 1048576 + p] = fmaf(rs, d[h] - m * su[h], cb[h] + bb[h]);
}

// ---------------- LN over D=256 rows (node_n, and FF pre-LN) ----------------
__global__ void ln_kernel(const float* __restrict__ x, const float* __restrict__ g,
                          const float* __restrict__ b, float* __restrict__ y) {
    const int row = blockIdx.x, t = threadIdx.x; // 64 threads
    float4 v = *(const float4*)(x + (size_t)row * 256 + (t << 2));
    float s1 = v.x + v.y + v.z + v.w;
    float s2 = v.x*v.x + v.y*v.y + v.z*v.z + v.w*v.w;
    #pragma unroll
    for (int o = 32; o > 0; o >>= 1) { s1 += __shfl_down(s1, o); s2 += __shfl_down(s2, o); }
    s1 = __shfl(s1, 0); s2 = __shfl(s2, 0);
    const float m = s1 * 0.00390625f;
    const float rs = rsqrtf(s2 * 0.00390625f - m * m + EPS_);
    float4 gv = *(const float4*)(g + (t << 2));
    float4 bv = *(const float4*)(b + (t << 2));
    float4 o4;
    o4.x = (v.x - m) * rs * gv.x + bv.x;
    o4.y = (v.y - m) * rs * gv.y + bv.y;
    o4.z = (v.z - m) * rs * gv.z + bv.z;
    o4.w = (v.w - m) * rs * gv.w + bv.w;
    *(float4*)(y + (size_t)row * 256 + (t << 2)) = o4;
}

// ---------------- generic 64x64-tile fp32 GEMM, 4x4 per thread ----------------
// flags: 1=relu, 2=+bias, 4=+residual ; atrans: A stored [K][M]
__device__ __forceinline__ void gemm64_core(
    const float* __restrict__ A, const float* __restrict__ W,
    const float* __restrict__ bias, const float* __restrict__ resid,
    float* __restrict__ outp, int M, int Nn, int K, int flags, bool atrans)
{
    __shared__ float At[16][68];
    __shared__ float Wt[16][68];
    const int n0 = blockIdx.x * 64;
    const int i0 = blockIdx.y * 64;
    const int t = threadIdx.x;
    const int tn = t & 15, ti = t >> 4;
    float acc[4][4] = {};

    for (int k0 = 0; k0 < K; k0 += 16) {
        __syncthreads();
        if (atrans) {
            const int kk = t >> 4, r4 = (t & 15) << 2;
            *(float4*)&At[kk][r4] = *(const float4*)(A + (size_t)(k0 + kk) * M + i0 + r4);
        } else {
            const int r = t >> 2, c4 = (t & 3) << 2;
            float4 a4 = *(const float4*)(A + (size_t)(i0 + r) * K + k0 + c4);
            At[c4 + 0][r] = a4.x; At[c4 + 1][r] = a4.y;
            At[c4 + 2][r] = a4.z; At[c4 + 3][r] = a4.w;
        }
        {
            const int kk = t >> 4, c4 = (t & 15) << 2;
            *(float4*)&Wt[kk][c4] = *(const float4*)(W + (size_t)(k0 + kk) * Nn + n0 + c4);
        }
        __syncthreads();
        #pragma unroll
        for (int kk = 0; kk < 16; kk++) {
            float a[4], w[4];
            *(float4*)a = *(const float4*)&At[kk][ti << 2];
            *(float4*)w = *(const float4*)&Wt[kk][tn << 2];
            #pragma unroll
            for (int r = 0; r < 4; r++)
                #pragma unroll
                for (int c = 0; c < 4; c++)
                    acc[r][c] = fmaf(a[r], w[c], acc[r][c]);
        }
    }

    float bvv[4] = {0.f, 0.f, 0.f, 0.f};
    if (flags & 2) {
        float4 b4 = *(const float4*)(bias + n0 + (tn << 2));
        bvv[0] = b4.x; bvv[1] = b4.y; bvv[2] = b4.z; bvv[3] = b4.w;
    }
    #pragma unroll
    for (int r = 0; r < 4; r++) {
        const int i = i0 + (ti << 2) + r;
        float o[4];
        #pragma unroll
        for (int c = 0; c < 4; c++) {
            o[c] = acc[r][c] + bvv[c];
            if (flags & 1) o[c] = fmaxf(o[c], 0.f);
        }
        if (flags & 4) {
            float4 r4 = *(const float4*)(resid + (size_t)i * Nn + n0 + (tn << 2));
            o[0] += r4.x; o[1] += r4.y; o[2] += r4.z; o[3] += r4.w;
        }
        *(float4*)(outp + (size_t)i * Nn + n0 + (tn << 2)) = make_float4(o[0], o[1], o[2], o[3]);
    }
}

__global__ __launch_bounds__(256) void gemm64_kernel(
    const float* A, const float* W, const float* bias, const float* resid,
    float* outp, int M, int Nn, int K, int flags, int atrans) {
    gemm64_core(A, W, bias, resid, outp, M, Nn, K, flags, atrans != 0);
}

__global__ __launch_bounds__(256) void gemm_qkvg_kernel(
    const float* A, const float* W0, const float* W1_, const float* W2_, const float* W3_,
    float* outbase, int M, int Nn, int K) {
    const float* W = (blockIdx.z == 0) ? W0 : (blockIdx.z == 1) ? W1_ : (blockIdx.z == 2) ? W2_ : W3_;
    float* outp = outbase + (size_t)blockIdx.z * 393216;
    gemm64_core(A, W, nullptr, nullptr, outp, M, Nn, K, 0, false);
}

// ---------------- RoPE on q (pre-scaled by 1/16) and k ----------------
__global__ void rope_kernel(const float* __restrict__ qr, const float* __restrict__ kr,
                            const float* __restrict__ pos,
                            float* __restrict__ q, float* __restrict__ k) {
    int id = blockIdx.x * 256 + threadIdx.x; // 1024*8*24
    if (id >= 196608) return;
    int dd = id % 24;
    int h = (id / 24) & 7;
    int i = id / 192;
    float p = pos[i];
    float inv = __powf(10000.0f, -(float)dd * (1.0f / 24.0f));
    float th = p * inv;
    float s, c;
    __sincosf(th, &s, &c);
    size_t base = (size_t)i * 384 + h * 48;
    float x1 = qr[base + dd], x2 = qr[base + 24 + dd];
    q[base + dd]      = (x1 * c - x2 * s) * 0.0625f;
    q[base + 24 + dd] = (x1 * s + x2 * c) * 0.0625f;
    x1 = kr[base + dd]; x2 = kr[base + 24 + dd];
    k[base + dd]      = x1 * c - x2 * s;
    k[base + 24 + dd] = x1 * s + x2 * c;
}

// ---------------- K3a: S[h][i][j] += q.k + mask (in-place on b_term) ----------------
__global__ __launch_bounds__(256) void scores_kernel(
    const float* __restrict__ q, const float* __restrict__ k,
    const float* __restrict__ mask, float* __restrict__ S)
{
    __shared__ float Qt[48][68];
    __shared__ float Kt[48][68];
    const int j0 = blockIdx.x * 64, i0 = blockIdx.y * 64, h = blockIdx.z;
    const int t = threadIdx.x;
    #pragma unroll
    for (int l = 0; l < 3; l++) {
        int idx = l * 256 + t;
        int r = idx / 12, c4 = (idx % 12) << 2;
        float4 a4 = *(const float4*)(q + (size_t)(i0 + r) * 384 + h * 48 + c4);
        Qt[c4 + 0][r] = a4.x; Qt[c4 + 1][r] = a4.y; Qt[c4 + 2][r] = a4.z; Qt[c4 + 3][r] = a4.w;
        float4 b4 = *(const float4*)(k + (size_t)(j0 + r) * 384 + h * 48 + c4);
        Kt[c4 + 0][r] = b4.x; Kt[c4 + 1][r] = b4.y; Kt[c4 + 2][r] = b4.z; Kt[c4 + 3][r] = b4.w;
    }
    __syncthreads();
    const int tj = t & 15, ti = t >> 4;
    float acc[4][4] = {};
    #pragma unroll 4
    for (int dd = 0; dd < 48; dd++) {
        float a[4], b[4];
        *(float4*)a = *(const float4*)&Qt[dd][ti << 2];
        *(float4*)b = *(const float4*)&Kt[dd][tj << 2];
        #pragma unroll
        for (int r = 0; r < 4; r++)
            #pragma unroll
            for (int c = 0; c < 4; c++)
                acc[r][c] = fmaf(a[r], b[c], acc[r][c]);
    }
    float4 mj = *(const float4*)(mask + j0 + (tj << 2));
    float mjv[4] = {mj.x, mj.y, mj.z, mj.w};
    #pragma unroll
    for (int r = 0; r < 4; r++) {
        const int i = i0 + (ti << 2) + r;
        const float mi = mask[i];
        size_t off = (size_t)h * 1048576 + (size_t)i * 1024 + j0 + (tj << 2);
        float4 s4 = *(float4*)(S + off);
        float o[4] = {s4.x, s4.y, s4.z, s4.w};
        #pragma unroll
        for (int c = 0; c < 4; c++)
            o[c] += acc[r][c] + INF_ * (mi * mjv[c] - 1.0f);
        *(float4*)(S + off) = make_float4(o[0], o[1], o[2], o[3]);
    }
}

// ---------------- K3b: per-(i,h) row max and sum(exp) ----------------
__global__ __launch_bounds__(256) void smax_kernel(
    const float* __restrict__ S, float* __restrict__ marr, float* __restrict__ larr)
{
    __shared__ float red[4];
    __shared__ float red2[4];
    const int i = blockIdx.x, h = blockIdx.y, t = threadIdx.x;
    const float* row = S + (size_t)h * 1048576 + (size_t)i * 1024;
    float4 v = *(const float4*)(row + (t << 2));
    float mx = fmaxf(fmaxf(v.x, v.y), fmaxf(v.z, v.w));
    #pragma unroll
    for (int o = 32; o > 0; o >>= 1) mx = fmaxf(mx, __shfl_down(mx, o));
    const int wave = t >> 6, lane = t & 63;
    if (lane == 0) red[wave] = mx;
    __syncthreads();
    mx = fmaxf(fmaxf(red[0], red[1]), fmaxf(red[2], red[3]));
    float e = __expf(v.x - mx) + __expf(v.y - mx) + __expf(v.z - mx) + __expf(v.w - mx);
    #pragma unroll
    for (int o = 32; o > 0; o >>= 1) e += __shfl_down(e, o);
    if (lane == 0) red2[wave] = e;
    __syncthreads();
    if (t == 0) {
        marr[h * 1024 + i] = mx;
        larr[h * 1024 + i] = red2[0] + red2[1] + red2[2] + red2[3];
    }
}

// ---------------- K3c: O^T[h][d][i] = sigmoid(gate) * sum_j softmax(S) V ----------------
__global__ __launch_bounds__(192) void pv_kernel(
    const float* __restrict__ S, const float* __restrict__ marr, const float* __restrict__ larr,
    const float* __restrict__ v, const float* __restrict__ graw, const float* __restrict__ bg,
    float* __restrict__ Ot)
{
    __shared__ float Pt[128][68]; // [j][i]
    __shared__ float Vt[128][52]; // [j][d]
    __shared__ float ml[64], il[64];
    const int i0 = blockIdx.x * 64, h = blockIdx.y;
    const int t = threadIdx.x; // 192
    if (t < 64) {
        ml[t] = marr[h * 1024 + i0 + t];
        il[t] = 1.0f / larr[h * 1024 + i0 + t];
    }
    __syncthreads();
    const int td = t % 12, tig = t / 12;
    float acc[4][4] = {};
    for (int j0 = 0; j0 < 1024; j0 += 128) {
        __syncthreads();
        for (int l = 0; l < 11; l++) {
            int idx = l * 192 + t;
            if (idx < 2048) {
                int r = idx >> 5, c4 = (idx & 31) << 2;
                float4 s4 = *(const float4*)(S + (size_t)h * 1048576 + (size_t)(i0 + r) * 1024 + j0 + c4);
                float mm = ml[r], ii = il[r];
                Pt[c4 + 0][r] = __expf(s4.x - mm) * ii;
                Pt[c4 + 1][r] = __expf(s4.y - mm) * ii;
                Pt[c4 + 2][r] = __expf(s4.z - mm) * ii;
                Pt[c4 + 3][r] = __expf(s4.w - mm) * ii;
            }
        }
        #pragma unroll
        for (int l = 0; l < 8; l++) {
            int idx = l * 192 + t;
            int jj = idx / 12, c4 = (idx % 12) << 2;
            *(float4*)&Vt[jj][c4] = *(const float4*)(v + (size_t)(j0 + jj) * 384 + h * 48 + c4);
        }
        __syncthreads();
        #pragma unroll 4
        for (int jj = 0; jj < 128; jj++) {
            float vv[4], pp[4];
            *(float4*)vv = *(const float4*)&Vt[jj][td << 2];
            *(float4*)pp = *(const float4*)&Pt[jj][tig << 2];
            #pragma unroll
            for (int a = 0; a < 4; a++)
                #pragma unroll
                for (int b = 0; b < 4; b++)
                    acc[a][b] = fmaf(vv[a], pp[b], acc[a][b]);
        }
    }
    #pragma unroll
    for (int a = 0; a < 4; a++) {
        const int dd = (td << 2) + a;
        float o[4];
        #pragma unroll
        for (int b = 0; b < 4; b++) {
            const int i = i0 + (tig << 2) + b;
            float gv = graw[(size_t)i * 384 + h * 48 + dd] + bg[h * 48 + dd];
            float sg = 1.0f / (1.0f + __expf(-gv));
            o[b] = acc[a][b] * sg;
        }
        *(float4*)(Ot + (size_t)h * 49152 + (size_t)dd * 1024 + i0 + (tig << 2))
            = make_float4(o[0], o[1], o[2], o[3]);
    }
}

// ---------------- launch ----------------
extern "C" void kernel_launch(void* const* d_in, const int* in_sizes, int n_in,
                              void* d_out, int out_size, void* d_ws, size_t ws_size,
                              hipStream_t stream)
{
    const float* node   = (const float*)d_in[0];
    const float* edge   = (const float*)d_in[1];
    const float* biasT  = (const float*)d_in[2];
    const float* pos    = (const float*)d_in[3];
    const float* mask   = (const float*)d_in[4];
    const float* g_node = (const float*)d_in[5];
    const float* b_node = (const float*)d_in[6];
    const float* g_edge = (const float*)d_in[7];
    const float* b_edge = (const float*)d_in[8];
    const float* W_bias = (const float*)d_in[9];
    const float* Wq     = (const float*)d_in[10];
    const float* Wk     = (const float*)d_in[11];
    const float* Wv     = (const float*)d_in[12];
    const float* Wb     = (const float*)d_in[13];
    const float* Wg     = (const float*)d_in[14];
    const float* bg     = (const float*)d_in[15];
    const float* Wo     = (const float*)d_in[16];
    const float* g_ff   = (const float*)d_in[17];
    const float* b_ff   = (const float*)d_in[18];
    const float* W1     = (const float*)d_in[19];
    const float* b1     = (const float*)d_in[20];
    const float* W2     = (const float*)d_in[21];
    const float* b2     = (const float*)d_in[22];
    float* ws  = (float*)d_ws;
    float* out = (float*)d_out;

    prep_kernel<<<dim3(1), dim3(512), 0, stream>>>(g_edge, b_edge, W_bias, Wb, ws);
    bterm_kernel<<<dim3(4096), dim3(256), 0, stream>>>(
        edge, biasT, ws + O_U, ws + O_WBB, ws + O_SU, ws + O_CB, ws + O_BT);
    ln_kernel<<<dim3(1024), dim3(64), 0, stream>>>(node, g_node, b_node, ws + O_NN);
    gemm_qkvg_kernel<<<dim3(6, 16, 4), dim3(256), 0, stream>>>(
        ws + O_NN, Wq, Wk, Wv, Wg, ws + O_QR, 1024, 384, 256);
    rope_kernel<<<dim3(768), dim3(256), 0, stream>>>(
        ws + O_QR, ws + O_KR, pos, ws + O_Q, ws + O_K);
    scores_kernel<<<dim3(16, 16, 8), dim3(256), 0, stream>>>(
        ws + O_Q, ws + O_K, mask, ws + O_BT);
    smax_kernel<<<dim3(1024, 8), dim3(256), 0, stream>>>(ws + O_BT, ws + O_M, ws + O_L);
    pv_kernel<<<dim3(16, 8), dim3(192), 0, stream>>>(
        ws + O_BT, ws + O_M, ws + O_L, ws + O_V, ws + O_GR, bg, ws + O_OT);
    gemm64_kernel<<<dim3(4, 16), dim3(256), 0, stream>>>(
        ws + O_OT, Wo, nullptr, nullptr, ws + O_G, 1024, 256, 384, 0, 1);
    ln_kernel<<<dim3(1024), dim3(64), 0, stream>>>(ws + O_G, g_ff, b_ff, ws + O_GN);
    gemm64_kernel<<<dim3(8, 16), dim3(256), 0, stream>>>(
        ws + O_GN, W1, b1, nullptr, ws + O_H1, 1024, 512, 256, 3, 0);
    gemm64_kernel<<<dim3(4, 16), dim3(256), 0, stream>>>(
        ws + O_H1, W2, b2, node, out, 1024, 256, 512, 6, 0);
}